// Round 6
// baseline (758.578 us; speedup 1.0000x reference)
//
#include <hip/hip_runtime.h>
#include <stdint.h>

typedef unsigned short u16;
typedef unsigned char  u8;
typedef unsigned int   u32;

#define NG   512
#define NPG  200
#define EPG  6400
#define HID  128
#define CS   136          // h1t row stride in u16 ([v][c], 272B rows, 16B aligned)
#define MS   232          // M row stride in u16 ([cout][s], 464B rows, 16B aligned)
#define SR   50           // dst rows per slice (4 slices, padded to 64 for MFMA)
#define SPAD 232          // count-matrix row stride in LDS (u8)
#define ASZ  57344        // per-graph swizzled A-frag bytes: 4q*2wA*2mi*7ks*64lane*8B

__device__ __forceinline__ float bf2f(u16 b){ u32 u = ((u32)b) << 16; return __builtin_bit_cast(float, u); }
__device__ __forceinline__ u16 f2bf(float f){
    u32 u = __builtin_bit_cast(u32, f);
    u = (u + 0x7FFFu + ((u >> 16) & 1u)) >> 16;
    return (u16)u;
}
// two bytes of w (at sh, sh+8) -> packed bf16x2 (exact for ints < 256: truncation)
__device__ __forceinline__ u32 cvt2bf(u32 w, int sh){
    float f0 = (float)((w >> sh) & 0xFFu);
    float f1 = (float)((w >> (sh + 8)) & 0xFFu);
    return __builtin_amdgcn_perm(__builtin_bit_cast(u32, f1), __builtin_bit_cast(u32, f0), 0x07060302);
}

typedef __attribute__((ext_vector_type(8))) short bf16x8;
typedef __attribute__((ext_vector_type(4))) float f32x4;

// canon arena (fp32): vectors only
enum : int { cW1=0, cb1=128, cb2=256, cba=384, cbb=896, cbc=1920, cbd=2944, cWe=3456, cbe=8576, cEND=8586 };
// WTa arena (bf16 [n][k])
enum : int { T_Wa=0, T_Wb=65536, T_Wc=589824, T_Wd=1638400, T_END=2162688 };

struct PrepIn { const void* p[14]; };

// ---------------------------------------------------------------------------
// Grid barrier: all NG blocks co-resident by construction (LDS 65376B -> 2/CU,
// launch_bounds(512,4) caps VGPR<=128 -> 2/CU; grid = 256CU*2 exactly).
// threadfence = agent-scope release/acquire (L2 writeback/inv) for cross-XCD
// visibility (G16). Counters zeroed by hipMemsetAsync before launch.
// ---------------------------------------------------------------------------
__device__ __forceinline__ void gbar(u32* bar, int i){
    __syncthreads();
    if (threadIdx.x == 0){
        __threadfence();
        __hip_atomic_fetch_add(&bar[i], 1u, __ATOMIC_RELEASE, __HIP_MEMORY_SCOPE_AGENT);
        while (__hip_atomic_load(&bar[i], __ATOMIC_ACQUIRE, __HIP_MEMORY_SCOPE_AGENT) < (u32)NG)
            __builtin_amdgcn_s_sleep(2);
        __threadfence();
    }
    __syncthreads();
}

// ---------------------------------------------------------------------------
// MLP phase: 4-way K-split, tile 16 x (NFR*32), logical grid (32,16) mapped
// from block id. hi/lo bf16 split MFMA, depth-1 prefetch, 3-way LDS reduce.
// ---------------------------------------------------------------------------
template<int K, int NFR>
__device__ __forceinline__ void mlp_phase(u32* shm,
    const u16* __restrict__ Ahi, const u16* __restrict__ Alo,
    const u16* __restrict__ WT, const float* __restrict__ bias,
    u16* __restrict__ Ohi, u16* __restrict__ Olo, int Nc, int g)
{
    constexpr int KQ = K/4, ITERS = KQ/32, NTILE = NFR*32;
    float* red = (float*)shm;                      // [3][16][68] = 13056 B

    const int tid = threadIdx.x;
    const int w = tid >> 6, lane = tid & 63;
    const int kz = w >> 1, wn = w & 1;
    const int lr = lane & 15, quad = lane >> 4;
    const int row0 = (g & 31) * 16, col0 = (g >> 5) * NTILE;
    const size_t m = row0 + lr;
    const int k0 = kz * KQ;

    auto loadA = [&](int it, bf16x8& hi, bf16x8& lo){
        const int kk = k0 + it*32 + quad*8;
        hi = *(const bf16x8*)&Ahi[m*K + kk];
        lo = *(const bf16x8*)&Alo[m*K + kk];
    };
    auto loadB = [&](int it, bf16x8* b){
        const int kk = k0 + it*32 + quad*8;
        #pragma unroll
        for (int nt = 0; nt < NFR; nt++){
            int n = col0 + wn*(NFR*16) + nt*16 + lr;
            b[nt] = *(const bf16x8*)&WT[(size_t)n*K + kk];
        }
    };

    const f32x4 fz = {0.f, 0.f, 0.f, 0.f};
    f32x4 acc[NFR];
    #pragma unroll
    for (int nt = 0; nt < NFR; nt++) acc[nt] = fz;
    bf16x8 chi, clo, cb[NFR], nhi, nlo, nb[NFR];
    loadA(0, chi, clo); loadB(0, cb);
    #pragma unroll
    for (int it = 0; it < ITERS; it++){
        if (it + 1 < ITERS){ loadA(it+1, nhi, nlo); loadB(it+1, nb); }
        #pragma unroll
        for (int nt = 0; nt < NFR; nt++){
            acc[nt] = __builtin_amdgcn_mfma_f32_16x16x32_bf16(chi, cb[nt], acc[nt], 0, 0, 0);
            acc[nt] = __builtin_amdgcn_mfma_f32_16x16x32_bf16(clo, cb[nt], acc[nt], 0, 0, 0);
        }
        chi = nhi; clo = nlo;
        #pragma unroll
        for (int nt = 0; nt < NFR; nt++) cb[nt] = nb[nt];
    }

    if (kz > 0){
        #pragma unroll
        for (int nt = 0; nt < NFR; nt++)
            #pragma unroll
            for (int r = 0; r < 4; r++)
                red[(((kz-1)*16 + quad*4 + r)*68) + wn*(NFR*16) + nt*16 + lr] = acc[nt][r];
    }
    __syncthreads();
    if (kz == 0){
        #pragma unroll
        for (int nt = 0; nt < NFR; nt++)
            #pragma unroll
            for (int r = 0; r < 4; r++){
                int rr = quad*4 + r;
                int cc = wn*(NFR*16) + nt*16 + lr;
                float v = acc[nt][r] + red[(0*16+rr)*68+cc] + red[(1*16+rr)*68+cc]
                        + red[(2*16+rr)*68+cc] + bias[col0 + cc];
                v = fmaxf(v, 0.f);
                u16 hh = f2bf(v);
                size_t go = (size_t)(row0 + rr) * Nc + col0 + cc;
                Ohi[go] = hh;
                Olo[go] = f2bf(v - bf2f(hh));
            }
    }
}

// ---------------------------------------------------------------------------
// K_fused: entire pipeline in ONE dispatch (was 6). Phases separated by grid
// barriers; block g owns graph g in build/mega/head and tile (g&31, g>>5) in
// the MLP phases. t/io/ii persist in LDS from build to mega (tioG deleted).
// LDS 65376 B: [0..60927]=cnt/tile/HB/red arena, [60928..65375]=persist.
// ---------------------------------------------------------------------------
__global__ __launch_bounds__(512, 4) void k_fused(
    PrepIn in,
    const int* __restrict__ src, const int* __restrict__ dst,
    float* __restrict__ canon, u16* __restrict__ W2T, u16* __restrict__ WTa,
    u8* __restrict__ AG8S,
    u16* __restrict__ X1hi, u16* __restrict__ X1lo,
    u16* __restrict__ X2hi, u16* __restrict__ X2lo,
    u16* __restrict__ X3hi, u16* __restrict__ X3lo,
    u16* __restrict__ X4hi, u16* __restrict__ X4lo,
    void* __restrict__ out, u32* __restrict__ bar)
{
    __shared__ __align__(16) u32 shm[16344];       // 65376 B -> 2 blocks/CU

    const int g = blockIdx.x, tid = threadIdx.x;

    // persistent region (survives build -> mega)
    float* tL    = (float*)&shm[15232];
    float* ioLp  = (float*)&shm[15432];
    float* iiLp  = (float*)&shm[15632];
    float* w1L   = (float*)&shm[15832];
    float* b1L   = (float*)&shm[15960];
    float* b2L   = (float*)&shm[16088];
    float* poolL = (float*)&shm[16216];

    //=========================== PHASE 1: build ===========================
    {
        u32*   cnt  = shm;                         // 11600 u32 = 200x232 u8
        u32*   dio  = shm + 11600;                 // in<<16 | out
        float* sVal = (float*)(shm + 11800);

        uint4* c4 = (uint4*)cnt;
        #pragma unroll
        for (int i = 0; i < 6; i++){
            int idx = i*512 + tid;
            if (idx < 2900) c4[idx] = make_uint4(0,0,0,0);
        }
        if (tid < NPG) dio[tid] = 0u;
        __syncthreads();

        const int ebase = g * EPG;
        const int2* s2 = (const int2*)(src + ebase);
        const int2* d2 = (const int2*)(dst + ebase);
        #pragma unroll
        for (int i = 0; i < 7; i++){
            int e = i*512 + tid;
            if (e < EPG/2){
                int2 ss = s2[e], dd = d2[e];
                int s0 = ss.x - g*NPG, d0 = dd.x - g*NPG;
                int s1 = ss.y - g*NPG, d1 = dd.y - g*NPG;
                atomicAdd(&dio[s0], 1u);  atomicAdd(&dio[d0], 0x10000u);
                atomicAdd(&dio[s1], 1u);  atomicAdd(&dio[d1], 0x10000u);
                int i0 = d0*SPAD + s0, i1 = d1*SPAD + s1;
                atomicAdd(&cnt[i0 >> 2], 1u << (8*(i0 & 3)));
                atomicAdd(&cnt[i1 >> 2], 1u << (8*(i1 & 3)));
            }
        }
        __syncthreads();
        if (tid < NPG){
            u32 u = dio[tid];
            float din = (float)(u >> 16), dout = (float)(u & 0xFFFFu);
            float ii = rsqrtf(fmaxf(din, 1.f));
            float io = rsqrtf(fmaxf(dout, 1.f));
            iiLp[tid] = ii; ioLp[tid] = io;
            sVal[tid] = din * io;          // h0 = in_deg; s = h0*inv_out
        }
        __syncthreads();
        // t[d] = ii[d] * sum_s cnt[d][s]*sVal[s]
        if (tid < NPG){
            const u32* row = cnt + tid*(SPAD/4);
            float acc = 0.f;
            #pragma unroll
            for (int j = 0; j < 50; j++){
                u32 wv = row[j];
                acc = fmaf((float)( wv        & 0xFFu), sVal[4*j+0], acc);
                acc = fmaf((float)((wv >>  8) & 0xFFu), sVal[4*j+1], acc);
                acc = fmaf((float)((wv >> 16) & 0xFFu), sVal[4*j+2], acc);
                acc = fmaf((float)( wv >> 24        ), sVal[4*j+3], acc);
            }
            tL[tid] = acc * iiLp[tid];
        }
        // swizzled A-frag export: chunk gi = f*64 + lane, f = ((q*2+wA)*2+mi)*7+ks
        u8* As = AG8S + (size_t)g*ASZ;
        #pragma unroll
        for (int i = 0; i < 14; i++){
            int gi = i*512 + tid;               // 7168 uint2 chunks
            int lane2 = gi & 63, fidx = gi >> 6;
            int ks = fidx % 7, t2 = fidx / 7;
            int mi = t2 & 1, t3 = t2 >> 1;
            int wA2 = t3 & 1, q = t3 >> 1;
            int r = q*SR + wA2*32 + mi*16 + (lane2 & 15);
            int c = ks*32 + (lane2 >> 4)*8;
            uint2 v = make_uint2(0u, 0u);
            if (r < NPG){
                const u32* p = cnt + (r*SPAD + c)/4;
                v = make_uint2(p[0], p[1]);
            }
            *(uint2*)(As + (size_t)gi*8) = v;
        }
    }

    //====================== PHASE 1b: prep units ==========================
    {
        __syncthreads();                           // cnt dead; reuse as tile
        u16* tile  = (u16*)shm;                    // [64][72] = 9216 B
        int* sflag = (int*)&shm[5000];
        if (tid < 64){
            const u16* wb = (const u16*)in.p[0];
            u16 a = wb[tid], b = wb[64 + tid];
            unsigned long long m1 = __ballot((int)((a >> 7) & 0xFF) >= 0x7F);
            unsigned long long m2 = __ballot((int)((b >> 7) & 0xFF) >= 0x7F);
            if (tid == 0) *sflag = (__popcll(m1) + __popcll(m2) > 4) ? 1 : 0;
        }
        __syncthreads();
        const int f = *sflag;

        for (int u = g; u < 549; u += NG){         // blocks 0..36 take 2 units
            __syncthreads();                       // tile reuse guard
            if (u < 532){
                const void* s; u16* dst_; int K, N, t, lgn;
                if      (u < 4)  { t = u;       s = in.p[2];  dst_ = W2T;        K = 128;  N = 128;  lgn = 1; }
                else if (u < 20) { t = u - 4;   s = in.p[4];  dst_ = WTa + T_Wa; K = 128;  N = 512;  lgn = 3; }
                else if (u < 148){ t = u - 20;  s = in.p[6];  dst_ = WTa + T_Wb; K = 512;  N = 1024; lgn = 4; }
                else if (u < 404){ t = u - 148; s = in.p[8];  dst_ = WTa + T_Wc; K = 1024; N = 1024; lgn = 4; }
                else             { t = u - 404; s = in.p[10]; dst_ = WTa + T_Wd; K = 1024; N = 512;  lgn = 3; }
                const int k0 = (t >> lgn) * 64, n0 = (t & ((1 << lgn) - 1)) * 64;
                #pragma unroll
                for (int i = 0; i < 2; i++){
                    int idx = i*512 + tid;           // 64 kk x 16 nn-groups
                    int kk = idx >> 4, nn0 = (idx & 15)*4;
                    int si = (k0 + kk)*N + n0 + nn0;
                    if (f){
                        float4 fv = *(const float4*)&((const float*)s)[si];
                        tile[(nn0+0)*72+kk] = f2bf(fv.x); tile[(nn0+1)*72+kk] = f2bf(fv.y);
                        tile[(nn0+2)*72+kk] = f2bf(fv.z); tile[(nn0+3)*72+kk] = f2bf(fv.w);
                    } else {
                        uint2 uv = *(const uint2*)&((const u16*)s)[si];
                        tile[(nn0+0)*72+kk] = (u16)(uv.x & 0xFFFF); tile[(nn0+1)*72+kk] = (u16)(uv.x >> 16);
                        tile[(nn0+2)*72+kk] = (u16)(uv.y & 0xFFFF); tile[(nn0+3)*72+kk] = (u16)(uv.y >> 16);
                    }
                }
                __syncthreads();
                #pragma unroll
                for (int i = 0; i < 2; i++){
                    int idx = i*512 + tid;           // 64 nn x 16 kk-groups
                    int nn = idx >> 4, kk0 = (idx & 15)*4;
                    uint2 val = *(const uint2*)&tile[nn*72 + kk0];
                    *(uint2*)&dst_[(size_t)(n0 + nn)*K + k0 + kk0] = val;
                }
            } else {
                int i = (u - 532)*512 + tid;
                if (i < cEND){
                    const void* s; int off;
                    if      (i < 128) { s = in.p[0];  off = i; }
                    else if (i < 256) { s = in.p[1];  off = i - 128; }
                    else if (i < 384) { s = in.p[3];  off = i - 256; }
                    else if (i < 896) { s = in.p[5];  off = i - 384; }
                    else if (i < 1920){ s = in.p[7];  off = i - 896; }
                    else if (i < 2944){ s = in.p[9];  off = i - 1920; }
                    else if (i < 3456){ s = in.p[11]; off = i - 2944; }
                    else if (i < 8576){ s = in.p[12]; off = i - 3456; }
                    else              { s = in.p[13]; off = i - 8576; }
                    canon[i] = f ? ((const float*)s)[off] : bf2f(((const u16*)s)[off]);
                }
            }
        }
    }

    gbar(bar, 0);   // canon/W2T/WTa/AG8S ready device-wide

    //=========================== PHASE 2: mega ============================
    {
        u16* HB = (u16*)shm;                       // [224][CS] then M [128][MS]
        if (tid < HID){
            w1L[tid] = canon[cW1 + tid]; b1L[tid] = canon[cb1 + tid];
            b2L[tid] = canon[cb2 + tid]; poolL[tid] = 0.f;
        }
        __syncthreads();

        // P4: h1t[v][c] = bf16( relu(t*w1+b1) * io ), rows v>=200 zero
        #pragma unroll
        for (int i = 0; i < 7; i++){
            int idx = i*512 + tid;                 // 224 rows x 16 c-groups
            int v = idx >> 4, c0 = (idx & 15)*8;
            bf16x8 o8 = {0,0,0,0,0,0,0,0};
            if (v < NPG){
                float tv = tL[v], iov = ioLp[v];
                float4 wa = *(const float4*)&w1L[c0];
                float4 wb = *(const float4*)&w1L[c0+4];
                float4 bA = *(const float4*)&b1L[c0];
                float4 bB = *(const float4*)&b1L[c0+4];
                float ww[8] = {wa.x, wa.y, wa.z, wa.w, wb.x, wb.y, wb.z, wb.w};
                float bb[8] = {bA.x, bA.y, bA.z, bA.w, bB.x, bB.y, bB.z, bB.w};
                #pragma unroll
                for (int j = 0; j < 8; j++)
                    o8[j] = (short)f2bf(fmaxf(fmaf(tv, ww[j], bb[j]), 0.f) * iov);
            }
            *(bf16x8*)&HB[v*CS + c0] = o8;
        }
        __syncthreads();

        const int w = tid >> 6, lane = tid & 63;
        const int lr = lane & 15, quad = lane >> 4;
        const int wA = w >> 2, wB = w & 3;
        const f32x4 fz = {0.f, 0.f, 0.f, 0.f};

        // M-GEMM: Mt[s=224][cout=128] = h1t @ W2
        f32x4 accM[7][2];
        #pragma unroll
        for (int mi = 0; mi < 7; mi++){ accM[mi][0] = fz; accM[mi][1] = fz; }
        #pragma unroll
        for (int ks = 0; ks < 4; ks++){
            bf16x8 bw[2];
            #pragma unroll
            for (int nt = 0; nt < 2; nt++)
                bw[nt] = *(const bf16x8*)&W2T[(size_t)(wB*32 + nt*16 + lr)*HID + ks*32 + quad*8];
            #pragma unroll
            for (int mi = 0; mi < 7; mi++){
                bf16x8 ah = *(const bf16x8*)&HB[(wA*112 + mi*16 + lr)*CS + ks*32 + quad*8];
                #pragma unroll
                for (int nt = 0; nt < 2; nt++)
                    accM[mi][nt] = __builtin_amdgcn_mfma_f32_16x16x32_bf16(ah, bw[nt], accM[mi][nt], 0, 0, 0);
            }
        }
        __syncthreads();   // h1t reads done before overwrite

        #pragma unroll
        for (int mi = 0; mi < 7; mi++)
            #pragma unroll
            for (int nt = 0; nt < 2; nt++){
                int cout = wB*32 + nt*16 + lr;
                int s0   = wA*112 + mi*16 + quad*4;
                u16 z0 = f2bf(accM[mi][nt][0]), z1 = f2bf(accM[mi][nt][1]);
                u16 z2 = f2bf(accM[mi][nt][2]), z3 = f2bf(accM[mi][nt][3]);
                uint2 pk = { (u32)z0 | ((u32)z1 << 16), (u32)z2 | ((u32)z3 << 16) };
                *(uint2*)&HB[cout*MS + s0] = pk;
            }
        __syncthreads();   // M ready; slice loop barrier-free

        const float b2c[2] = { b2L[wB*32 + lr], b2L[wB*32 + 16 + lr] };
        float pacc[2] = {0.f, 0.f};
        const u8* Abase = AG8S + (size_t)g*ASZ;
        const int lane8 = lane*8;
        auto aload = [&](int q, int mi, int ks){
            return *(const uint2*)(Abase + (size_t)(((((q*2 + wA)*2 + mi)*7 + ks) << 9) + lane8));
        };

        uint2 brA[2][7], brB[2][7];
        #pragma unroll
        for (int mi = 0; mi < 2; mi++)
            #pragma unroll
            for (int ks = 0; ks < 7; ks++)
                brA[mi][ks] = aload(0, mi, ks);

        for (int q = 0; q < 4; q++){
            if (q < 3){
                #pragma unroll
                for (int mi = 0; mi < 2; mi++)
                    #pragma unroll
                    for (int ks = 0; ks < 7; ks++)
                        brB[mi][ks] = aload(q+1, mi, ks);
            }
            f32x4 acc[2][2] = {{fz, fz}, {fz, fz}};
            #pragma unroll
            for (int ks = 0; ks < 7; ks++){
                bf16x8 bm[2];
                #pragma unroll
                for (int nt = 0; nt < 2; nt++)
                    bm[nt] = *(const bf16x8*)&HB[(wB*32 + nt*16 + lr)*MS + ks*32 + quad*8];
                #pragma unroll
                for (int mi = 0; mi < 2; mi++){
                    u32 lo = brA[mi][ks].x, hi = brA[mi][ks].y;
                    union { uint4 u; bf16x8 v; } cvu;
                    cvu.u = make_uint4(cvt2bf(lo, 0), cvt2bf(lo, 16), cvt2bf(hi, 0), cvt2bf(hi, 16));
                    #pragma unroll
                    for (int nt = 0; nt < 2; nt++)
                        acc[mi][nt] = __builtin_amdgcn_mfma_f32_16x16x32_bf16(cvu.v, bm[nt], acc[mi][nt], 0, 0, 0);
                }
            }
            #pragma unroll
            for (int mi = 0; mi < 2; mi++)
                #pragma unroll
                for (int nt = 0; nt < 2; nt++)
                    #pragma unroll
                    for (int r = 0; r < 4; r++){
                        int vq = wA*32 + mi*16 + quad*4 + r;
                        if (vq < SR)
                            pacc[nt] += fmaxf(fmaf(acc[mi][nt][r], iiLp[q*SR + vq], b2c[nt]), 0.f);
                    }
            #pragma unroll
            for (int mi = 0; mi < 2; mi++)
                #pragma unroll
                for (int ks = 0; ks < 7; ks++) brA[mi][ks] = brB[mi][ks];
        }

        #pragma unroll
        for (int nt = 0; nt < 2; nt++){
            float v = pacc[nt];
            v += __shfl_down(v, 32);
            v += __shfl_down(v, 16);
            if (quad == 0) atomicAdd(&poolL[wB*32 + nt*16 + lr], v);
        }
        __syncthreads();

        // fused mlp_a: X1[g][c=tid] = relu( (pool/200) . Wa[:,c] + ba[c] )
        const u16* wrow = WTa + T_Wa + (size_t)tid * HID;
        float dot = 0.f;
        #pragma unroll
        for (int kk = 0; kk < HID; kk += 8){
            bf16x8 wv = *(const bf16x8*)&wrow[kk];
            float4 p0 = *(const float4*)&poolL[kk];
            float4 p1 = *(const float4*)&poolL[kk + 4];
            float pp[8] = {p0.x, p0.y, p0.z, p0.w, p1.x, p1.y, p1.z, p1.w};
            #pragma unroll
            for (int j = 0; j < 8; j++)
                dot = fmaf(pp[j], bf2f((u16)wv[j]), dot);
        }
        float xv = fmaxf(dot * (1.f/NPG) + canon[cba + tid], 0.f);
        u16 hh = f2bf(xv);
        X1hi[(size_t)g*512 + tid] = hh;
        X1lo[(size_t)g*512 + tid] = f2bf(xv - bf2f(hh));
    }

    gbar(bar, 1);
    mlp_phase<512,  2>(shm, X1hi, X1lo, WTa + T_Wb, canon + cbb, X2hi, X2lo, 1024, g);
    gbar(bar, 2);
    mlp_phase<1024, 2>(shm, X2hi, X2lo, WTa + T_Wc, canon + cbc, X3hi, X3lo, 1024, g);
    gbar(bar, 3);
    mlp_phase<1024, 1>(shm, X3hi, X3lo, WTa + T_Wd, canon + cbd, X4hi, X4lo, 512, g);
    gbar(bar, 4);

    //=========================== PHASE 6: head ============================
    if (tid < 64){
        const int lane = tid;
        const u16* w1bits = (const u16*)in.p[0];
        u16 a = w1bits[lane], b = w1bits[64 + lane];
        unsigned long long m1 = __ballot((int)((a >> 7) & 0xFF) >= 0x7F);
        unsigned long long m2 = __ballot((int)((b >> 7) & 0xFF) >= 0x7F);
        const int f = (__popcll(m1) + __popcll(m2) > 4) ? 1 : 0;
        const float* We = canon + cWe;
        const float* be = canon + cbe;

        bf16x8 xh = *(const bf16x8*)&X4hi[(size_t)g*512 + lane*8];
        bf16x8 xl = *(const bf16x8*)&X4lo[(size_t)g*512 + lane*8];

        float part[10];
        #pragma unroll
        for (int c = 0; c < 10; c++) part[c] = 0.f;
        #pragma unroll
        for (int j = 0; j < 8; j++){
            float xv = bf2f((u16)xh[j]) + bf2f((u16)xl[j]);
            const float* wr = &We[(size_t)(lane*8 + j)*10];
            #pragma unroll
            for (int c = 0; c < 10; c++) part[c] = fmaf(xv, wr[c], part[c]);
        }
        #pragma unroll
        for (int c = 0; c < 10; c++){
            float v = part[c];
            for (int off = 32; off > 0; off >>= 1) v += __shfl_down(v, off);
            part[c] = v;
        }
        if (lane == 0){
            #pragma unroll
            for (int c = 0; c < 10; c++) part[c] += be[c];
            float m = part[0];
            #pragma unroll
            for (int c = 1; c < 10; c++) m = fmaxf(m, part[c]);
            float e[10], s = 0.f;
            #pragma unroll
            for (int c = 0; c < 10; c++){ e[c] = __expf(part[c] - m); s += e[c]; }
            float inv = 1.f / s;
            #pragma unroll
            for (int c = 0; c < 10; c++){
                float p = e[c] * inv;
                if (f) ((float*)out)[g*10 + c] = p;
                else   ((u16*)out)[g*10 + c]  = f2bf(p);
            }
        }
    }
}

// ---------------------------------------------------------------------------
extern "C" void kernel_launch(void* const* d_in, const int* in_sizes, int n_in,
                              void* d_out, int out_size, void* d_ws, size_t ws_size,
                              hipStream_t stream)
{
    const int* src = (const int*)d_in[0];
    const int* dst = (const int*)d_in[1];

    char* ws = (char*)d_ws;
    size_t o = 0;
    float* canon    = (float*)(ws + o); o += ((size_t)cEND * 4 + 15) & ~(size_t)15;
    u16*   W2T      = (u16*)  (ws + o); o += (size_t)HID * HID * 2;
    u16*   WTa      = (u16*)  (ws + o); o += ((size_t)T_END * 2 + 15) & ~(size_t)15;
    u16*   X1hi     = (u16*)  (ws + o); o += (size_t)NG * 512 * 2;
    u16*   X1lo     = (u16*)  (ws + o); o += (size_t)NG * 512 * 2;
    u16*   X2hi     = (u16*)  (ws + o); o += (size_t)NG * 1024 * 2;
    u16*   X2lo     = (u16*)  (ws + o); o += (size_t)NG * 1024 * 2;
    u16*   X3hi     = (u16*)  (ws + o); o += (size_t)NG * 1024 * 2;
    u16*   X3lo     = (u16*)  (ws + o); o += (size_t)NG * 1024 * 2;
    u16*   X4hi     = (u16*)  (ws + o); o += (size_t)NG * 512 * 2;
    u16*   X4lo     = (u16*)  (ws + o); o += (size_t)NG * 512 * 2;
    o = (o + 15) & ~(size_t)15;
    u8*    AG8S     = (u8*)   (ws + o); o += (size_t)NG * ASZ;
    o = (o + 15) & ~(size_t)15;
    u32*   bar      = (u32*)  (ws + o); o += 64;
    (void)ws_size; (void)in_sizes; (void)n_in; (void)out_size;

    // zero grid-barrier counters (workspace is poisoned between iterations)
    hipMemsetAsync(bar, 0, 32, stream);

    PrepIn pin;
    for (int i = 0; i < 14; i++) pin.p[i] = d_in[2 + i];

    // entire pipeline: ONE dispatch, 512 blocks (all co-resident), 5 grid bars
    k_fused<<<dim3(NG), dim3(512), 0, stream>>>(pin, src, dst, canon, W2T, WTa,
                                                AG8S, X1hi, X1lo, X2hi, X2lo,
                                                X3hi, X3lo, X4hi, X4lo,
                                                d_out, bar);
}

// Round 7
// 187.134 us; speedup vs baseline: 4.0537x; 4.0537x over previous
//
#include <hip/hip_runtime.h>
#include <stdint.h>

typedef unsigned short u16;
typedef unsigned char  u8;
typedef unsigned int   u32;

#define NG   512
#define NPG  200
#define EPG  6400
#define HID  128
#define CS   136          // h1t row stride in u16 ([v][c], 272B rows, 16B aligned)
#define MS   232          // M row stride in u16 ([cout][s], 464B rows, 16B aligned)
#define SR   50           // dst rows per slice (4 slices, padded to 64 for MFMA)
#define SPAD 232          // count-matrix row stride in LDS (u8)
#define ASZ  57344        // per-graph swizzled A-frag bytes: 4q*2wA*2mi*7ks*64lane*8B

__device__ __forceinline__ float bf2f(u16 b){ u32 u = ((u32)b) << 16; return __builtin_bit_cast(float, u); }
__device__ __forceinline__ u16 f2bf(float f){
    u32 u = __builtin_bit_cast(u32, f);
    u = (u + 0x7FFFu + ((u >> 16) & 1u)) >> 16;
    return (u16)u;
}
// two bytes of w (at sh, sh+8) -> packed bf16x2 (exact for ints < 256: truncation)
__device__ __forceinline__ u32 cvt2bf(u32 w, int sh){
    float f0 = (float)((w >> sh) & 0xFFu);
    float f1 = (float)((w >> (sh + 8)) & 0xFFu);
    return __builtin_amdgcn_perm(__builtin_bit_cast(u32, f1), __builtin_bit_cast(u32, f0), 0x07060302);
}

typedef __attribute__((ext_vector_type(8))) short bf16x8;
typedef __attribute__((ext_vector_type(4))) float f32x4;

// canon arena (fp32): vectors only
enum : int { cW1=0, cb1=128, cb2=256, cba=384, cbb=896, cbc=1920, cbd=2944, cWe=3456, cbe=8576, cEND=8586 };
// WTa arena (bf16 [n][k])
enum : int { T_Wa=0, T_Wb=65536, T_Wc=589824, T_Wd=1638400, T_END=2162688 };

// ---------------------------------------------------------------------------
// K_pb: fused prep + build (independent work, disjoint block ranges).
//  blocks 0..511    : per-graph topology build (LDS atomics at 3 blocks/CU)
//  blocks 512..1043 : LDS-tiled weight transposes (vectorized both phases)
//  blocks 1044..1060: canon vector copies
// Build outputs AG8S (u8 counts PRE-SWIZZLED in MFMA-fragment order so k_mega's
// A-loads are fully coalesced; rows>=200 zeroed) + tioG[g][608] = {t, io, ii}.
// ---------------------------------------------------------------------------
struct PrepIn { const void* p[14]; };

__global__ __launch_bounds__(512) void k_pb(PrepIn in,
    const int* __restrict__ src, const int* __restrict__ dst,
    float* __restrict__ canon, u16* __restrict__ W2T, u16* __restrict__ WTa,
    u8* __restrict__ AG8S, float* __restrict__ tioG)
{
    __shared__ __align__(16) u32 shm[12600];   // 50400 B -> 3 blocks/CU
    const int tid = threadIdx.x;
    const int bid = blockIdx.x;

    if (bid < 512){
        // ---------------- build ----------------
        u32*   cnt  = shm;                       // 11600 u32 = 200x232 u8
        u32*   dio  = shm + 11600;               // 200 (in<<16 | out)
        float* sVal = (float*)(shm + 11800);
        float* ioL  = (float*)(shm + 12000);
        float* iiL  = (float*)(shm + 12200);
        const int g = bid;

        uint4* c4 = (uint4*)cnt;
        #pragma unroll
        for (int i = 0; i < 6; i++){
            int idx = i*512 + tid;
            if (idx < 2900) c4[idx] = make_uint4(0,0,0,0);
        }
        if (tid < NPG) dio[tid] = 0u;
        __syncthreads();

        const int ebase = g * EPG;
        const int2* s2 = (const int2*)(src + ebase);
        const int2* d2 = (const int2*)(dst + ebase);
        // single pass: degrees + counts
        #pragma unroll
        for (int i = 0; i < 7; i++){
            int e = i*512 + tid;
            if (e < EPG/2){
                int2 ss = s2[e], dd = d2[e];
                int s0 = ss.x - g*NPG, d0 = dd.x - g*NPG;
                int s1 = ss.y - g*NPG, d1 = dd.y - g*NPG;
                atomicAdd(&dio[s0], 1u);  atomicAdd(&dio[d0], 0x10000u);
                atomicAdd(&dio[s1], 1u);  atomicAdd(&dio[d1], 0x10000u);
                int i0 = d0*SPAD + s0, i1 = d1*SPAD + s1;
                atomicAdd(&cnt[i0 >> 2], 1u << (8*(i0 & 3)));
                atomicAdd(&cnt[i1 >> 2], 1u << (8*(i1 & 3)));
            }
        }
        __syncthreads();
        if (tid < NPG){
            u32 u = dio[tid];
            float din = (float)(u >> 16), dout = (float)(u & 0xFFFFu);
            float ii = rsqrtf(fmaxf(din, 1.f));
            float io = rsqrtf(fmaxf(dout, 1.f));
            iiL[tid] = ii; ioL[tid] = io;
            sVal[tid] = din * io;          // h0 = in_deg; s = h0*inv_out
        }
        __syncthreads();
        // t[d] = ii[d] * sum_s cnt[d][s]*sVal[s]  (row-dot, replaces atomics)
        if (tid < NPG){
            const u32* row = cnt + tid*(SPAD/4);
            float acc = 0.f;
            #pragma unroll
            for (int j = 0; j < 50; j++){
                u32 wv = row[j];
                acc = fmaf((float)( wv        & 0xFFu), sVal[4*j+0], acc);
                acc = fmaf((float)((wv >>  8) & 0xFFu), sVal[4*j+1], acc);
                acc = fmaf((float)((wv >> 16) & 0xFFu), sVal[4*j+2], acc);
                acc = fmaf((float)( wv >> 24        ), sVal[4*j+3], acc);
            }
            tioG[(size_t)g*608 + tid]       = acc * iiL[tid];
            tioG[(size_t)g*608 + 200 + tid] = ioL[tid];
            tioG[(size_t)g*608 + 400 + tid] = iiL[tid];
        }
        // swizzled A-frag export: chunk gi = f*64 + lane, f = ((q*2+wA)*2+mi)*7+ks
        // k_mega reads 512B contiguous per wave per frag.
        u8* As = AG8S + (size_t)g*ASZ;
        #pragma unroll
        for (int i = 0; i < 14; i++){
            int gi = i*512 + tid;               // 7168 uint2 chunks, exact
            int lane2 = gi & 63, fidx = gi >> 6;
            int ks = fidx % 7, t2 = fidx / 7;
            int mi = t2 & 1, t3 = t2 >> 1;
            int wA2 = t3 & 1, q = t3 >> 1;
            int r = q*SR + wA2*32 + mi*16 + (lane2 & 15);
            int c = ks*32 + (lane2 >> 4)*8;
            uint2 v = make_uint2(0u, 0u);
            if (r < NPG){
                const u32* p = cnt + (r*SPAD + c)/4;
                v = make_uint2(p[0], p[1]);
            }
            *(uint2*)(As + (size_t)gi*8) = v;
        }
    } else {
        // ---------------- prep ----------------
        u16* tile  = (u16*)shm;                  // [64][72]
        int* sflag = (int*)(shm + 12599);
        if (tid < 64){
            const u16* wb = (const u16*)in.p[0];
            u16 a = wb[tid], b = wb[64 + tid];
            unsigned long long m1 = __ballot((int)((a >> 7) & 0xFF) >= 0x7F);
            unsigned long long m2 = __ballot((int)((b >> 7) & 0xFF) >= 0x7F);
            if (tid == 0) *sflag = (__popcll(m1) + __popcll(m2) > 4) ? 1 : 0;
        }
        __syncthreads();
        const int f = *sflag;
        const int pb = bid - 512;

        if (pb < 532){
            const void* s; u16* dst_; int K, N, t, lgn;
            if      (pb < 4)  { t = pb;       s = in.p[2];  dst_ = W2T;        K = 128;  N = 128;  lgn = 1; }
            else if (pb < 20) { t = pb - 4;   s = in.p[4];  dst_ = WTa + T_Wa; K = 128;  N = 512;  lgn = 3; }
            else if (pb < 148){ t = pb - 20;  s = in.p[6];  dst_ = WTa + T_Wb; K = 512;  N = 1024; lgn = 4; }
            else if (pb < 404){ t = pb - 148; s = in.p[8];  dst_ = WTa + T_Wc; K = 1024; N = 1024; lgn = 4; }
            else              { t = pb - 404; s = in.p[10]; dst_ = WTa + T_Wd; K = 1024; N = 512;  lgn = 3; }
            const int k0 = (t >> lgn) * 64, n0 = (t & ((1 << lgn) - 1)) * 64;
            #pragma unroll
            for (int i = 0; i < 2; i++){
                int idx = i*512 + tid;               // 64 kk x 16 nn-groups
                int kk = idx >> 4, nn0 = (idx & 15)*4;
                int si = (k0 + kk)*N + n0 + nn0;
                if (f){
                    float4 fv = *(const float4*)&((const float*)s)[si];
                    tile[(nn0+0)*72+kk] = f2bf(fv.x); tile[(nn0+1)*72+kk] = f2bf(fv.y);
                    tile[(nn0+2)*72+kk] = f2bf(fv.z); tile[(nn0+3)*72+kk] = f2bf(fv.w);
                } else {
                    uint2 uv = *(const uint2*)&((const u16*)s)[si];
                    tile[(nn0+0)*72+kk] = (u16)(uv.x & 0xFFFF); tile[(nn0+1)*72+kk] = (u16)(uv.x >> 16);
                    tile[(nn0+2)*72+kk] = (u16)(uv.y & 0xFFFF); tile[(nn0+3)*72+kk] = (u16)(uv.y >> 16);
                }
            }
            __syncthreads();
            #pragma unroll
            for (int i = 0; i < 2; i++){
                int idx = i*512 + tid;               // 64 nn x 16 kk-groups
                int nn = idx >> 4, kk0 = (idx & 15)*4;
                uint2 val = *(const uint2*)&tile[nn*72 + kk0];
                *(uint2*)&dst_[(size_t)(n0 + nn)*K + k0 + kk0] = val;
            }
        } else {
            int i = (pb - 532)*512 + tid;
            if (i < cEND){
                const void* s; int off;
                if      (i < 128) { s = in.p[0];  off = i; }
                else if (i < 256) { s = in.p[1];  off = i - 128; }
                else if (i < 384) { s = in.p[3];  off = i - 256; }
                else if (i < 896) { s = in.p[5];  off = i - 384; }
                else if (i < 1920){ s = in.p[7];  off = i - 896; }
                else if (i < 2944){ s = in.p[9];  off = i - 1920; }
                else if (i < 3456){ s = in.p[11]; off = i - 2944; }
                else if (i < 8576){ s = in.p[12]; off = i - 3456; }
                else              { s = in.p[13]; off = i - 8576; }
                canon[i] = f ? ((const float*)s)[off] : bf2f(((const u16*)s)[off]);
            }
        }
    }
}

// ---------------------------------------------------------------------------
// K_mega v7: like v6 (M-restructure, coalesced swizzled A-loads, perm convert)
// but SINGLE-buffered A-frag loads: the 14 uint2 loads for slice q issue as
// one independent batch at the top of the q-iteration (AG8S is L2/L3-hot,
// ~300cy once per q, hidden by 16 waves/CU). Saves 28 VGPRs of prefetch state
// -> comfortably under the 128-VGPR/4-waves-per-EU cap, no spill risk.
// A-frag: A[m=lr][k=quad*8+j]; B-frag: B[k=quad*8+j][n=lr]; C/D: col=lr,row=quad*4+r
// ---------------------------------------------------------------------------
__global__ __launch_bounds__(512, 4) void k_mega(
    const u8* __restrict__ AG8S, const float* __restrict__ tioG,
    const float* __restrict__ W1, const float* __restrict__ b1,
    const float* __restrict__ b2, const u16* __restrict__ W2T,
    const u16* __restrict__ WTaA, const float* __restrict__ ba,
    u16* __restrict__ X1hi, u16* __restrict__ X1lo)
{
    __shared__ __align__(16) u16 HB[224*CS];       // 60928 B: h1t, then M
    __shared__ float tL[NPG], ioL[NPG], iiL[NPG];
    __shared__ __align__(16) float w1L[HID], b1L[HID];
    __shared__ float b2L[HID];
    __shared__ __align__(16) float poolL[HID];
    // total 65376 B -> 2 blocks/CU

    const int g = blockIdx.x, tid = threadIdx.x;
    if (tid < NPG){
        tL[tid]  = tioG[(size_t)g*608 + tid];
        ioL[tid] = tioG[(size_t)g*608 + 200 + tid];
        iiL[tid] = tioG[(size_t)g*608 + 400 + tid];
    }
    if (tid < HID){ w1L[tid] = W1[tid]; b1L[tid] = b1[tid]; b2L[tid] = b2[tid]; poolL[tid] = 0.f; }
    __syncthreads();

    // P4: h1t[v][c] = bf16( relu(t*w1+b1) * io ), rows v>=200 zero
    #pragma unroll
    for (int i = 0; i < 7; i++){
        int idx = i*512 + tid;                     // 224 rows x 16 c-groups
        int v = idx >> 4, c0 = (idx & 15)*8;
        bf16x8 out = {0,0,0,0,0,0,0,0};
        if (v < NPG){
            float tv = tL[v], iov = ioL[v];
            float4 wa = *(const float4*)&w1L[c0];
            float4 wb = *(const float4*)&w1L[c0+4];
            float4 bA = *(const float4*)&b1L[c0];
            float4 bB = *(const float4*)&b1L[c0+4];
            float ww[8] = {wa.x, wa.y, wa.z, wa.w, wb.x, wb.y, wb.z, wb.w};
            float bb[8] = {bA.x, bA.y, bA.z, bA.w, bB.x, bB.y, bB.z, bB.w};
            #pragma unroll
            for (int j = 0; j < 8; j++)
                out[j] = (short)f2bf(fmaxf(fmaf(tv, ww[j], bb[j]), 0.f) * iov);
        }
        *(bf16x8*)&HB[v*CS + c0] = out;
    }
    __syncthreads();

    const int w = tid >> 6, lane = tid & 63;
    const int lr = lane & 15, quad = lane >> 4;
    const int wA = w >> 2, wB = w & 3;             // wA: s/v-half; wB: cout-group
    const f32x4 fz = {0.f, 0.f, 0.f, 0.f};

    // M-GEMM: Mt[s=224][cout=128] = h1t @ W2 ; wave = 7 m-frags x 2 n-frags
    f32x4 accM[7][2];
    #pragma unroll
    for (int mi = 0; mi < 7; mi++){ accM[mi][0] = fz; accM[mi][1] = fz; }
    #pragma unroll
    for (int ks = 0; ks < 4; ks++){
        bf16x8 bw[2];
        #pragma unroll
        for (int nt = 0; nt < 2; nt++)
            bw[nt] = *(const bf16x8*)&W2T[(size_t)(wB*32 + nt*16 + lr)*HID + ks*32 + quad*8];
        #pragma unroll
        for (int mi = 0; mi < 7; mi++){
            bf16x8 ah = *(const bf16x8*)&HB[(wA*112 + mi*16 + lr)*CS + ks*32 + quad*8];
            #pragma unroll
            for (int nt = 0; nt < 2; nt++)
                accM[mi][nt] = __builtin_amdgcn_mfma_f32_16x16x32_bf16(ah, bw[nt], accM[mi][nt], 0, 0, 0);
        }
    }
    __syncthreads();   // all h1t reads complete before overwrite

    // write M[cout][s] (transposed C-write): 4 s-consecutive values -> b64
    #pragma unroll
    for (int mi = 0; mi < 7; mi++)
        #pragma unroll
        for (int nt = 0; nt < 2; nt++){
            int cout = wB*32 + nt*16 + lr;
            int s0   = wA*112 + mi*16 + quad*4;
            u16 z0 = f2bf(accM[mi][nt][0]), z1 = f2bf(accM[mi][nt][1]);
            u16 z2 = f2bf(accM[mi][nt][2]), z3 = f2bf(accM[mi][nt][3]);
            uint2 pk = { (u32)z0 | ((u32)z1 << 16), (u32)z2 | ((u32)z3 << 16) };
            *(uint2*)&HB[cout*MS + s0] = pk;
        }
    __syncthreads();   // M ready; slice loop below is barrier-free

    const float b2c[2] = { b2L[wB*32 + lr], b2L[wB*32 + 16 + lr] };
    float pacc[2] = {0.f, 0.f};
    const u8* Abase = AG8S + (size_t)g*ASZ;
    const int lane8 = lane*8;

    // coalesced A-frag load: frag f=((q*2+wA)*2+mi)*7+ks at Abase + f*512 + lane*8
    auto aload = [&](int q, int mi, int ks){
        return *(const uint2*)(Abase + (size_t)(((((q*2 + wA)*2 + mi)*7 + ks) << 9) + lane8));
    };

    for (int q = 0; q < 4; q++){
        // issue all 14 loads for this slice as one independent batch
        uint2 brA[2][7];
        #pragma unroll
        for (int mi = 0; mi < 2; mi++)
            #pragma unroll
            for (int ks = 0; ks < 7; ks++)
                brA[mi][ks] = aload(q, mi, ks);

        f32x4 acc[2][2] = {{fz, fz}, {fz, fz}};
        #pragma unroll
        for (int ks = 0; ks < 7; ks++){
            bf16x8 bm[2];
            #pragma unroll
            for (int nt = 0; nt < 2; nt++)
                bm[nt] = *(const bf16x8*)&HB[(wB*32 + nt*16 + lr)*MS + ks*32 + quad*8];
            #pragma unroll
            for (int mi = 0; mi < 2; mi++){
                u32 lo = brA[mi][ks].x, hi = brA[mi][ks].y;
                union { uint4 u; bf16x8 v; } cvu;
                cvu.u = make_uint4(cvt2bf(lo, 0), cvt2bf(lo, 16), cvt2bf(hi, 0), cvt2bf(hi, 16));
                #pragma unroll
                for (int nt = 0; nt < 2; nt++)
                    acc[mi][nt] = __builtin_amdgcn_mfma_f32_16x16x32_bf16(cvu.v, bm[nt], acc[mi][nt], 0, 0, 0);
            }
        }
        // epilogue: pacc += relu(H*ii + b2) for real rows
        #pragma unroll
        for (int mi = 0; mi < 2; mi++)
            #pragma unroll
            for (int nt = 0; nt < 2; nt++)
                #pragma unroll
                for (int r = 0; r < 4; r++){
                    int vq = wA*32 + mi*16 + quad*4 + r;
                    if (vq < SR)
                        pacc[nt] += fmaxf(fmaf(acc[mi][nt][r], iiL[q*SR + vq], b2c[nt]), 0.f);
                }
    }

    // pool reduce: quads via shuffle, then 1 atomic per 16 lanes per nt
    #pragma unroll
    for (int nt = 0; nt < 2; nt++){
        float v = pacc[nt];
        v += __shfl_down(v, 32);
        v += __shfl_down(v, 16);
        if (quad == 0) atomicAdd(&poolL[wB*32 + nt*16 + lr], v);
    }
    __syncthreads();

    // fused mlp_a: X1[g][c=tid] = relu( (pool/200) . Wa[:,c] + ba[c] ), fp32 dot
    {
        const u16* wrow = WTaA + (size_t)tid * HID;   // WTa row-major [512][128]
        float dot = 0.f;
        #pragma unroll
        for (int kk = 0; kk < HID; kk += 8){
            bf16x8 wv = *(const bf16x8*)&wrow[kk];
            float4 p0 = *(const float4*)&poolL[kk];
            float4 p1 = *(const float4*)&poolL[kk + 4];
            float pp[8] = {p0.x, p0.y, p0.z, p0.w, p1.x, p1.y, p1.z, p1.w};
            #pragma unroll
            for (int j = 0; j < 8; j++)
                dot = fmaf(pp[j], bf2f((u16)wv[j]), dot);
        }
        float v = fmaxf(dot * (1.f/NPG) + ba[tid], 0.f);
        u16 hh = f2bf(v);
        X1hi[(size_t)g*512 + tid] = hh;
        X1lo[(size_t)g*512 + tid] = f2bf(v - bf2f(hh));
    }
}

// ---------------------------------------------------------------------------
// MLP layer v7: 8-way K-split (all 8 waves on kz), tile 16x32, grids of
// 512-1024 blocks -> 4 blocks/CU, 32 waves/CU. Serial K-chain halves vs v6
// (ITERS 8->4 / 4->2). hi/lo bf16 split MFMA, depth-1 prefetch, 7-way LDS
// reduce on kz==0.
// ---------------------------------------------------------------------------
template<int K>
__global__ __launch_bounds__(512) void k_mlp7(
    const u16* __restrict__ Ahi, const u16* __restrict__ Alo,
    const u16* __restrict__ WT, const float* __restrict__ bias,
    u16* __restrict__ Ohi, u16* __restrict__ Olo, int Nc)
{
    constexpr int KO = K/8, ITERS = KO/32;
    __shared__ __align__(16) float red[7][16][36];   // 16128 B

    const int tid = threadIdx.x;
    const int kz = tid >> 6, lane = tid & 63;        // 8 kz-waves
    const int lr = lane & 15, quad = lane >> 4;
    const int row0 = blockIdx.x * 16, col0 = blockIdx.y * 32;
    const size_t m = row0 + lr;
    const int k0 = kz * KO;

    auto loadA = [&](int it, bf16x8& hi, bf16x8& lo){
        const int kk = k0 + it*32 + quad*8;
        hi = *(const bf16x8*)&Ahi[m*K + kk];
        lo = *(const bf16x8*)&Alo[m*K + kk];
    };
    auto loadB = [&](int it, bf16x8* b){
        const int kk = k0 + it*32 + quad*8;
        #pragma unroll
        for (int nt = 0; nt < 2; nt++){
            int n = col0 + nt*16 + lr;
            b[nt] = *(const bf16x8*)&WT[(size_t)n*K + kk];
        }
    };

    const f32x4 fz = {0.f, 0.f, 0.f, 0.f};
    f32x4 acc[2] = {fz, fz};
    bf16x8 chi, clo, cb[2], nhi, nlo, nb[2];
    loadA(0, chi, clo); loadB(0, cb);
    #pragma unroll
    for (int it = 0; it < ITERS; it++){
        if (it + 1 < ITERS){ loadA(it+1, nhi, nlo); loadB(it+1, nb); }
        #pragma unroll
        for (int nt = 0; nt < 2; nt++){
            acc[nt] = __builtin_amdgcn_mfma_f32_16x16x32_bf16(chi, cb[nt], acc[nt], 0, 0, 0);
            acc[nt] = __builtin_amdgcn_mfma_f32_16x16x32_bf16(clo, cb[nt], acc[nt], 0, 0, 0);
        }
        chi = nhi; clo = nlo; cb[0] = nb[0]; cb[1] = nb[1];
    }

    if (kz > 0){
        #pragma unroll
        for (int nt = 0; nt < 2; nt++)
            #pragma unroll
            for (int r = 0; r < 4; r++)
                red[kz-1][quad*4 + r][nt*16 + lr] = acc[nt][r];
    }
    __syncthreads();
    if (kz == 0){
        #pragma unroll
        for (int nt = 0; nt < 2; nt++)
            #pragma unroll
            for (int r = 0; r < 4; r++){
                int rr = quad*4 + r;
                int cc = nt*16 + lr;
                float v = acc[nt][r] + bias[col0 + cc];
                #pragma unroll
                for (int p = 0; p < 7; p++) v += red[p][rr][cc];
                v = fmaxf(v, 0.f);
                u16 hh = f2bf(v);
                size_t go = (size_t)(row0 + rr) * Nc + col0 + cc;
                Ohi[go] = hh;
                Olo[go] = f2bf(v - bf2f(hh));
            }
    }
}

// ---------------------------------------------------------------------------
// head v2: vectorized. lane owns k = lane*8..+7 (one bf16x8 pair), 80 FMA,
// then 10-class shuffle reduce + softmax on lane 0.
// ---------------------------------------------------------------------------
__global__ __launch_bounds__(64) void k_head(
    const u16* __restrict__ Xhi, const u16* __restrict__ Xlo,
    const float* __restrict__ We, const float* __restrict__ be,
    void* __restrict__ out, const u16* __restrict__ w1bits)
{
    const int g = blockIdx.x, lane = threadIdx.x;
    u16 a = w1bits[lane], b = w1bits[64 + lane];
    unsigned long long m1 = __ballot((int)((a >> 7) & 0xFF) >= 0x7F);
    unsigned long long m2 = __ballot((int)((b >> 7) & 0xFF) >= 0x7F);
    const int f = (__popcll(m1) + __popcll(m2) > 4) ? 1 : 0;

    bf16x8 xh = *(const bf16x8*)&Xhi[(size_t)g*512 + lane*8];
    bf16x8 xl = *(const bf16x8*)&Xlo[(size_t)g*512 + lane*8];

    float part[10];
    #pragma unroll
    for (int c = 0; c < 10; c++) part[c] = 0.f;
    #pragma unroll
    for (int j = 0; j < 8; j++){
        float xv = bf2f((u16)xh[j]) + bf2f((u16)xl[j]);
        const float* wr = &We[(size_t)(lane*8 + j)*10];
        #pragma unroll
        for (int c = 0; c < 10; c++) part[c] = fmaf(xv, wr[c], part[c]);
    }
    #pragma unroll
    for (int c = 0; c < 10; c++){
        float v = part[c];
        for (int off = 32; off > 0; off >>= 1) v += __shfl_down(v, off);
        part[c] = v;
    }
    if (lane == 0){
        #pragma unroll
        for (int c = 0; c < 10; c++) part[c] += be[c];
        float m = part[0];
        #pragma unroll
        for (int c = 1; c < 10; c++) m = fmaxf(m, part[c]);
        float e[10], s = 0.f;
        #pragma unroll
        for (int c = 0; c < 10; c++){ e[c] = __expf(part[c] - m); s += e[c]; }
        float inv = 1.f / s;
        #pragma unroll
        for (int c = 0; c < 10; c++){
            float p = e[c] * inv;
            if (f) ((float*)out)[g*10 + c] = p;
            else   ((u16*)out)[g*10 + c]  = f2bf(p);
        }
    }
}

// ---------------------------------------------------------------------------
extern "C" void kernel_launch(void* const* d_in, const int* in_sizes, int n_in,
                              void* d_out, int out_size, void* d_ws, size_t ws_size,
                              hipStream_t stream)
{
    const int* src = (const int*)d_in[0];
    const int* dst = (const int*)d_in[1];

    char* ws = (char*)d_ws;
    size_t o = 0;
    float* canon    = (float*)(ws + o); o += ((size_t)cEND * 4 + 15) & ~(size_t)15;
    u16*   W2T      = (u16*)  (ws + o); o += (size_t)HID * HID * 2;
    u16*   WTa      = (u16*)  (ws + o); o += ((size_t)T_END * 2 + 15) & ~(size_t)15;
    u16*   X1hi     = (u16*)  (ws + o); o += (size_t)NG * 512 * 2;
    u16*   X1lo     = (u16*)  (ws + o); o += (size_t)NG * 512 * 2;
    u16*   X2hi     = (u16*)  (ws + o); o += (size_t)NG * 1024 * 2;
    u16*   X2lo     = (u16*)  (ws + o); o += (size_t)NG * 1024 * 2;
    u16*   X3hi     = (u16*)  (ws + o); o += (size_t)NG * 1024 * 2;
    u16*   X3lo     = (u16*)  (ws + o); o += (size_t)NG * 1024 * 2;
    u16*   X4hi     = (u16*)  (ws + o); o += (size_t)NG * 512 * 2;
    u16*   X4lo     = (u16*)  (ws + o); o += (size_t)NG * 512 * 2;
    o = (o + 15) & ~(size_t)15;
    u8*    AG8S     = (u8*)   (ws + o); o += (size_t)NG * ASZ;
    float* tioG     = (float*)(ws + o); o += (size_t)NG * 608 * 4;
    (void)ws_size; (void)in_sizes; (void)n_in; (void)out_size;

    // fused prep + build (independent block ranges, one dispatch)
    PrepIn pin;
    for (int i = 0; i < 14; i++) pin.p[i] = d_in[2 + i];
    k_pb<<<dim3(1061), dim3(512), 0, stream>>>(pin, src, dst, canon, W2T, WTa, AG8S, tioG);

    const float *W1 = canon+cW1, *b1 = canon+cb1, *b2 = canon+cb2;
    const float *ba = canon+cba, *bb = canon+cbb, *bc = canon+cbc, *bd = canon+cbd;
    const float *We = canon+cWe, *be = canon+cbe;

    // mega: M-restructured, coalesced barrier-free slice loop + fused mlp_a
    k_mega<<<dim3(NG), dim3(512), 0, stream>>>(AG8S, tioG, W1, b1, b2, W2T,
                                               WTa + T_Wa, ba, X1hi, X1lo);

    // MLP: 8-way K-split, tile 16x32, 512-1024-block grids (4 blocks/CU)
    k_mlp7<512 ><<<dim3(32, 32), dim3(512), 0, stream>>>(X1hi, X1lo, WTa + T_Wb, bb, X2hi, X2lo, 1024);
    k_mlp7<1024><<<dim3(32, 32), dim3(512), 0, stream>>>(X2hi, X2lo, WTa + T_Wc, bc, X3hi, X3lo, 1024);
    k_mlp7<1024><<<dim3(32, 16), dim3(512), 0, stream>>>(X3hi, X3lo, WTa + T_Wd, bd, X4hi, X4lo, 512);

    // head + softmax
    k_head<<<dim3(NG), dim3(64), 0, stream>>>(X4hi, X4lo, We, be, d_out, (const u16*)d_in[2]);
}